// Round 1
// baseline (447.072 us; speedup 1.0000x reference)
//
#include <hip/hip_runtime.h>
#include <stdint.h>

#define B_ 256
#define L_ 196
#define C_ 2048
#define E_ 512
#define H_ 512
#define A_ 512
#define M_ (B_*L_)   // 50176

typedef __bf16 bf16x8 __attribute__((ext_vector_type(8)));
typedef float  f32x4  __attribute__((ext_vector_type(4)));

__device__ __forceinline__ unsigned short f2bf(float f) {
    union { float f; unsigned int u; } v; v.f = f;
    unsigned int r = 0x7FFFu + ((v.u >> 16) & 1u);
    return (unsigned short)((v.u + r) >> 16);
}

// ---------------- prep kernels ----------------

__global__ void k_cvt(const float* __restrict__ src, unsigned short* __restrict__ dst, int n4) {
    int i = blockIdx.x * blockDim.x + threadIdx.x;
    if (i < n4) {
        float4 v = ((const float4*)src)[i];
        ushort4 o; o.x = f2bf(v.x); o.y = f2bf(v.y); o.z = f2bf(v.z); o.w = f2bf(v.w);
        ((ushort4*)dst)[i] = o;
    }
}

// wcat[j][0:512]=Wi[j], [512:1024]=Wh[j], [1024:3072]=Wz[j]; bcat[j]=bi+bh+bz
__global__ void k_build_wcat(const float* __restrict__ Wi, const float* __restrict__ Wh,
                             const float* __restrict__ Wz, const float* __restrict__ bi,
                             const float* __restrict__ bh, const float* __restrict__ bz,
                             unsigned short* __restrict__ wcat, float* __restrict__ bcat) {
    int j = blockIdx.x;       // 2048
    int t = threadIdx.x;      // 256
    for (int g = t; g < 768; g += 256) {
        int k = g * 4;
        const float* src;
        if (k < 512)       src = Wi + j*512 + k;
        else if (k < 1024) src = Wh + j*512 + (k - 512);
        else               src = Wz + j*2048 + (k - 1024);
        float4 v = *(const float4*)src;
        ushort4 o; o.x = f2bf(v.x); o.y = f2bf(v.y); o.z = f2bf(v.z); o.w = f2bf(v.w);
        *(ushort4*)(wcat + (size_t)j*3072 + k) = o;
    }
    if (t == 0) bcat[j] = bi[j] + bh[j] + bz[j];
}

// xcat[b][0:512]=xt[b], [512:1024]=pre_h[b]  (z part written by k_z)
__global__ void k_build_xcat(const float* __restrict__ xt, const float* __restrict__ preh,
                             unsigned short* __restrict__ xcat) {
    int b = blockIdx.x, t = threadIdx.x;  // 256 threads
    const float* src = (t < 128) ? (xt + b*512 + t*4) : (preh + b*512 + (t-128)*4);
    int off = (t < 128) ? (t*4) : (512 + (t-128)*4);
    float4 v = *(const float4*)src;
    ushort4 o; o.x = f2bf(v.x); o.y = f2bf(v.y); o.z = f2bf(v.z); o.w = f2bf(v.w);
    *(ushort4*)(xcat + (size_t)b*3072 + off) = o;
}

// hlin[b][a] = pre_h[b]·Wha[a] + bha[a] + ba[a]   (ba folded in)
__global__ void k_hlin(const float* __restrict__ preh, const float* __restrict__ Wha,
                       const float* __restrict__ bha, const float* __restrict__ ba,
                       float* __restrict__ hlin) {
    __shared__ float ph[512];
    int b = blockIdx.x, t = threadIdx.x;   // 512 threads
    ph[t] = preh[b*512 + t];
    __syncthreads();
    float acc = bha[t] + ba[t];
    const float4* wrow = (const float4*)(Wha + (size_t)t*512);
    #pragma unroll 8
    for (int k4 = 0; k4 < 128; ++k4) {
        float4 v = wrow[k4];
        float4 p = *(const float4*)&ph[k4*4];
        acc += v.x*p.x + v.y*p.y + v.z*p.z + v.w*p.w;
    }
    hlin[b*512 + t] = acc;
}

// ---------------- fused scores GEMM ----------------
// scores[row] = bo + sum_a Wo[a] * tanh( att[row]·Wa[a] + hlin[b(row)][a] )
// block: 64 rows x all 512 cols, K=2048, BK=32, 4 waves (each 64x128)
#define K2_LDK 40

__global__ __launch_bounds__(256, 2) void k_scores(
    const float* __restrict__ att,          // [M_][C_] fp32
    const unsigned short* __restrict__ wa,  // [A_][C_] bf16
    const float* __restrict__ hlin,         // [B_][A_]
    const float* __restrict__ wo,           // [A_]
    const float* __restrict__ bo,           // [1]
    float* __restrict__ scores)             // [M_]
{
    __shared__ unsigned short lA[64 * K2_LDK];
    __shared__ unsigned short lB[512 * K2_LDK];
    __shared__ float red[4][64];

    const int tid = threadIdx.x;
    const int w = tid >> 6, l = tid & 63;
    const int l16 = l & 15, lq = l >> 4;
    const int row0 = blockIdx.x * 64;

    f32x4 acc[4][8];
    #pragma unroll
    for (int m = 0; m < 4; ++m)
        #pragma unroll
        for (int n = 0; n < 8; ++n) acc[m][n] = (f32x4){0.f, 0.f, 0.f, 0.f};

    for (int kt = 0; kt < C_/32; ++kt) {
        const int k0 = kt * 32;
        __syncthreads();
        // stage A: 64x32 fp32 -> bf16 (512 float4 groups, 2/thread)
        #pragma unroll
        for (int i = 0; i < 2; ++i) {
            int g = tid + i*256;
            int r = g >> 3, c4 = g & 7;
            float4 v = *(const float4*)(att + (size_t)(row0 + r)*C_ + k0 + c4*4);
            ushort4 o; o.x = f2bf(v.x); o.y = f2bf(v.y); o.z = f2bf(v.z); o.w = f2bf(v.w);
            *(ushort4*)&lA[r*K2_LDK + c4*4] = o;
        }
        // stage B: 512x32 bf16 (2048 ushort8 groups, 8/thread)
        #pragma unroll
        for (int i = 0; i < 8; ++i) {
            int g = tid + i*256;
            int r = g >> 2, c8 = g & 3;
            uint4 v = *(const uint4*)(wa + (size_t)r*C_ + k0 + c8*8);
            *(uint4*)&lB[r*K2_LDK + c8*8] = v;
        }
        __syncthreads();

        bf16x8 af[4];
        #pragma unroll
        for (int m = 0; m < 4; ++m)
            af[m] = *(const bf16x8*)&lA[(m*16 + l16)*K2_LDK + lq*8];
        #pragma unroll
        for (int n = 0; n < 8; ++n) {
            bf16x8 bfr = *(const bf16x8*)&lB[(w*128 + n*16 + l16)*K2_LDK + lq*8];
            #pragma unroll
            for (int m = 0; m < 4; ++m)
                acc[m][n] = __builtin_amdgcn_mfma_f32_16x16x32_bf16(af[m], bfr, acc[m][n], 0, 0, 0);
        }
    }

    // epilogue: tanh + dot(Wo) + reduce
    #pragma unroll
    for (int m = 0; m < 4; ++m) {
        #pragma unroll
        for (int r = 0; r < 4; ++r) {
            int lrow = m*16 + lq*4 + r;
            int grow = row0 + lrow;
            int bidx = grow / L_;
            float s = 0.f;
            #pragma unroll
            for (int n = 0; n < 8; ++n) {
                int col = w*128 + n*16 + l16;
                float v = acc[m][n][r] + hlin[bidx*A_ + col];
                s += tanhf(v) * wo[col];
            }
            s += __shfl_xor(s, 1);
            s += __shfl_xor(s, 2);
            s += __shfl_xor(s, 4);
            s += __shfl_xor(s, 8);
            if (l16 == 0) red[w][lrow] = s;
        }
    }
    __syncthreads();
    if (tid < 64) {
        float tot = red[0][tid] + red[1][tid] + red[2][tid] + red[3][tid] + bo[0];
        scores[row0 + tid] = tot;
    }
}

// ---------------- softmax over L per batch ----------------
__global__ void k_softmax(const float* __restrict__ scores, float* __restrict__ cw) {
    __shared__ float sm[4], ss[4];
    int b = blockIdx.x, t = threadIdx.x, w = t >> 6, l = t & 63;
    float v = (t < L_) ? scores[b*L_ + t] : -1e30f;
    float m = v;
    #pragma unroll
    for (int o = 1; o < 64; o <<= 1) m = fmaxf(m, __shfl_xor(m, o));
    if (l == 0) sm[w] = m;
    __syncthreads();
    m = fmaxf(fmaxf(sm[0], sm[1]), fmaxf(sm[2], sm[3]));
    float e = (t < L_) ? expf(v - m) : 0.f;
    float s = e;
    #pragma unroll
    for (int o = 1; o < 64; o <<= 1) s += __shfl_xor(s, o);
    if (l == 0) ss[w] = s;
    __syncthreads();
    s = ss[0] + ss[1] + ss[2] + ss[3];
    if (t < L_) cw[b*L_ + t] = e / s;
}

// ---------------- z = sum_l cw[b][l]*att[b][l][:] -> xcat bf16 ----------------
__global__ void k_z(const float* __restrict__ att, const float* __restrict__ cw,
                    unsigned short* __restrict__ xcat) {
    __shared__ float w_s[L_];
    int b = blockIdx.y, half = blockIdx.x, t = threadIdx.x;
    if (t < L_) w_s[t] = cw[b*L_ + t];
    __syncthreads();
    int c = half*1024 + t*4;
    const float* base = att + (size_t)b*L_*C_ + c;
    float ax = 0.f, ay = 0.f, az = 0.f, aw = 0.f;
    #pragma unroll 4
    for (int li = 0; li < L_; ++li) {
        float4 v = *(const float4*)(base + (size_t)li*C_);
        float wt = w_s[li];
        ax += wt*v.x; ay += wt*v.y; az += wt*v.z; aw += wt*v.w;
    }
    ushort4 o; o.x = f2bf(ax); o.y = f2bf(ay); o.z = f2bf(az); o.w = f2bf(aw);
    *(ushort4*)(xcat + (size_t)b*3072 + 1024 + c) = o;
}

// ---------------- GEMM2: S = xcat @ wcat^T + bcat ----------------
// M=256, N=2048, K=3072; block 64x128, 4 waves (each 64x32)
__global__ __launch_bounds__(256) void k_gemm2(
    const unsigned short* __restrict__ xcat,  // [256][3072] bf16
    const unsigned short* __restrict__ wcat,  // [2048][3072] bf16
    const float* __restrict__ bcat,           // [2048]
    float* __restrict__ S)                    // [256][2048]
{
    __shared__ unsigned short lA[64 * K2_LDK];
    __shared__ unsigned short lB[128 * K2_LDK];
    const int tid = threadIdx.x;
    const int w = tid >> 6, l = tid & 63;
    const int l16 = l & 15, lq = l >> 4;
    const int row0 = blockIdx.y * 64;
    const int col0 = blockIdx.x * 128;

    f32x4 acc[4][2];
    #pragma unroll
    for (int m = 0; m < 4; ++m)
        #pragma unroll
        for (int n = 0; n < 2; ++n) acc[m][n] = (f32x4){0.f, 0.f, 0.f, 0.f};

    for (int kt = 0; kt < 3072/32; ++kt) {
        const int k0 = kt * 32;
        __syncthreads();
        {   // A: 64x32 (256 groups, 1/thread)
            int r = tid >> 2, c8 = tid & 3;
            *(uint4*)&lA[r*K2_LDK + c8*8] =
                *(const uint4*)(xcat + (size_t)(row0 + r)*3072 + k0 + c8*8);
        }
        #pragma unroll
        for (int i = 0; i < 2; ++i) {  // B: 128x32 (512 groups, 2/thread)
            int g = tid + i*256;
            int r = g >> 2, c8 = g & 3;
            *(uint4*)&lB[r*K2_LDK + c8*8] =
                *(const uint4*)(wcat + (size_t)(col0 + r)*3072 + k0 + c8*8);
        }
        __syncthreads();

        bf16x8 af[4];
        #pragma unroll
        for (int m = 0; m < 4; ++m)
            af[m] = *(const bf16x8*)&lA[(m*16 + l16)*K2_LDK + lq*8];
        #pragma unroll
        for (int n = 0; n < 2; ++n) {
            bf16x8 bfr = *(const bf16x8*)&lB[(w*32 + n*16 + l16)*K2_LDK + lq*8];
            #pragma unroll
            for (int m = 0; m < 4; ++m)
                acc[m][n] = __builtin_amdgcn_mfma_f32_16x16x32_bf16(af[m], bfr, acc[m][n], 0, 0, 0);
        }
    }

    #pragma unroll
    for (int m = 0; m < 4; ++m)
        #pragma unroll
        for (int n = 0; n < 2; ++n)
            #pragma unroll
            for (int r = 0; r < 4; ++r) {
                int grow = row0 + m*16 + lq*4 + r;
                int col = col0 + w*32 + n*16 + l16;
                S[(size_t)grow*2048 + col] = acc[m][n][r] + bcat[col];
            }
}

// ---------------- LSTM gates ----------------
__global__ void k_lstm(const float* __restrict__ S, const float* __restrict__ prec,
                       float* __restrict__ out) {
    int b = blockIdx.x, h = threadIdx.x;  // 512 threads
    float ig = 1.f / (1.f + expf(-S[(size_t)b*2048 + h]));
    float fg = 1.f / (1.f + expf(-S[(size_t)b*2048 + 512 + h]));
    float og = 1.f / (1.f + expf(-S[(size_t)b*2048 + 1024 + h]));
    float gt = tanhf(S[(size_t)b*2048 + 1536 + h]);
    float c = fg * prec[b*512 + h] + ig * gt;
    out[b*512 + h] = og * tanhf(c);
    out[131072 + b*512 + h] = c;
}

// ---------------- launch ----------------
extern "C" void kernel_launch(void* const* d_in, const int* in_sizes, int n_in,
                              void* d_out, int out_size, void* d_ws, size_t ws_size,
                              hipStream_t stream) {
    const float* xt  = (const float*)d_in[0];
    const float* att = (const float*)d_in[1];
    const float* h0  = (const float*)d_in[2];
    const float* c0  = (const float*)d_in[3];
    const float* Wi  = (const float*)d_in[4];
    const float* bi  = (const float*)d_in[5];
    const float* Wh  = (const float*)d_in[6];
    const float* bh  = (const float*)d_in[7];
    const float* Wz  = (const float*)d_in[8];
    const float* bz  = (const float*)d_in[9];
    const float* Wa  = (const float*)d_in[10];
    const float* ba  = (const float*)d_in[11];
    const float* Wha = (const float*)d_in[12];
    const float* bha = (const float*)d_in[13];
    const float* Wo  = (const float*)d_in[14];
    const float* bo  = (const float*)d_in[15];
    float* out = (float*)d_out;

    char* ws = (char*)d_ws;
    unsigned short* wa_bf   = (unsigned short*)(ws);                       // 2 MB
    unsigned short* wcat_bf = (unsigned short*)(ws + 2097152);             // 12 MB
    unsigned short* xcat_bf = (unsigned short*)(ws + 14680064);            // 1.5 MB
    float* hlin   = (float*)(ws + 16252928);                               // 512 KB
    float* scores = (float*)(ws + 16777216);                               // 200 KB
    float* cw     = (float*)(ws + 16977920);                               // 200 KB
    float* bcat   = (float*)(ws + 17178624);                               // 8 KB
    float* S      = (float*)(ws + 17186816);                               // 2 MB

    k_cvt<<<1024, 256, 0, stream>>>(Wa, wa_bf, 262144);
    k_build_wcat<<<2048, 256, 0, stream>>>(Wi, Wh, Wz, bi, bh, bz, wcat_bf, bcat);
    k_build_xcat<<<256, 256, 0, stream>>>(xt, h0, xcat_bf);
    k_hlin<<<256, 512, 0, stream>>>(h0, Wha, bha, ba, hlin);
    k_scores<<<M_/64, 256, 0, stream>>>(att, wa_bf, hlin, Wo, bo, scores);
    k_softmax<<<256, 256, 0, stream>>>(scores, cw);
    k_z<<<dim3(2, 256), 256, 0, stream>>>(att, cw, xcat_bf);
    k_gemm2<<<dim3(16, 4), 256, 0, stream>>>(xcat_bf, wcat_bf, bcat, S);
    k_lstm<<<256, 512, 0, stream>>>(S, c0, out);
}

// Round 2
// 446.720 us; speedup vs baseline: 1.0008x; 1.0008x over previous
//
#include <hip/hip_runtime.h>
#include <stdint.h>

#define B_ 256
#define L_ 196
#define C_ 2048
#define E_ 512
#define H_ 512
#define A_ 512
#define M_ (B_*L_)   // 50176

typedef __bf16 bf16x8 __attribute__((ext_vector_type(8)));
typedef float  f32x4  __attribute__((ext_vector_type(4)));

__device__ __forceinline__ unsigned short f2bf(float f) {
    union { float f; unsigned int u; } v; v.f = f;
    unsigned int r = 0x7FFFu + ((v.u >> 16) & 1u);
    return (unsigned short)((v.u + r) >> 16);
}

// ---------------- prep kernels ----------------

__global__ void k_cvt(const float* __restrict__ src, unsigned short* __restrict__ dst, int n4) {
    int i = blockIdx.x * blockDim.x + threadIdx.x;
    if (i < n4) {
        float4 v = ((const float4*)src)[i];
        ushort4 o; o.x = f2bf(v.x); o.y = f2bf(v.y); o.z = f2bf(v.z); o.w = f2bf(v.w);
        ((ushort4*)dst)[i] = o;
    }
}

// wcat[j][0:512]=Wi[j], [512:1024]=Wh[j], [1024:3072]=Wz[j]; bcat[j]=bi+bh+bz
__global__ void k_build_wcat(const float* __restrict__ Wi, const float* __restrict__ Wh,
                             const float* __restrict__ Wz, const float* __restrict__ bi,
                             const float* __restrict__ bh, const float* __restrict__ bz,
                             unsigned short* __restrict__ wcat, float* __restrict__ bcat) {
    int j = blockIdx.x;       // 2048
    int t = threadIdx.x;      // 256
    for (int g = t; g < 768; g += 256) {
        int k = g * 4;
        const float* src;
        if (k < 512)       src = Wi + j*512 + k;
        else if (k < 1024) src = Wh + j*512 + (k - 512);
        else               src = Wz + j*2048 + (k - 1024);
        float4 v = *(const float4*)src;
        ushort4 o; o.x = f2bf(v.x); o.y = f2bf(v.y); o.z = f2bf(v.z); o.w = f2bf(v.w);
        *(ushort4*)(wcat + (size_t)j*3072 + k) = o;
    }
    if (t == 0) bcat[j] = bi[j] + bh[j] + bz[j];
}

// xcat[b][0:512]=xt[b], [512:1024]=pre_h[b]  (z part written by k_z)
__global__ void k_build_xcat(const float* __restrict__ xt, const float* __restrict__ preh,
                             unsigned short* __restrict__ xcat) {
    int b = blockIdx.x, t = threadIdx.x;  // 256 threads
    const float* src = (t < 128) ? (xt + b*512 + t*4) : (preh + b*512 + (t-128)*4);
    int off = (t < 128) ? (t*4) : (512 + (t-128)*4);
    float4 v = *(const float4*)src;
    ushort4 o; o.x = f2bf(v.x); o.y = f2bf(v.y); o.z = f2bf(v.z); o.w = f2bf(v.w);
    *(ushort4*)(xcat + (size_t)b*3072 + off) = o;
}

// hlin[b][a] = pre_h[b]·Wha[a] + bha[a] + ba[a]   (ba folded in)
__global__ void k_hlin(const float* __restrict__ preh, const float* __restrict__ Wha,
                       const float* __restrict__ bha, const float* __restrict__ ba,
                       float* __restrict__ hlin) {
    __shared__ float ph[512];
    int b = blockIdx.x, t = threadIdx.x;   // 512 threads
    ph[t] = preh[b*512 + t];
    __syncthreads();
    float acc = bha[t] + ba[t];
    const float4* wrow = (const float4*)(Wha + (size_t)t*512);
    #pragma unroll 8
    for (int k4 = 0; k4 < 128; ++k4) {
        float4 v = wrow[k4];
        float4 p = *(const float4*)&ph[k4*4];
        acc += v.x*p.x + v.y*p.y + v.z*p.z + v.w*p.w;
    }
    hlin[b*512 + t] = acc;
}

// ---------------- fused scores GEMM ----------------
// scores[row] = bo + sum_a Wo[a] * tanh( att[row]·Wa[a] + hlin[b(row)][a] )
// block: 64 rows x all 512 cols, K=2048, BK=32, 4 waves (each 64x128)
#define K2_LDK 40

__global__ __launch_bounds__(256, 2) void k_scores(
    const float* __restrict__ att,          // [M_][C_] fp32
    const unsigned short* __restrict__ wa,  // [A_][C_] bf16
    const float* __restrict__ hlin,         // [B_][A_]
    const float* __restrict__ wo,           // [A_]
    const float* __restrict__ bo,           // [1]
    float* __restrict__ scores)             // [M_]
{
    __shared__ unsigned short lA[64 * K2_LDK];
    __shared__ unsigned short lB[512 * K2_LDK];
    __shared__ float red[4][64];

    const int tid = threadIdx.x;
    const int w = tid >> 6, l = tid & 63;
    const int l16 = l & 15, lq = l >> 4;
    const int row0 = blockIdx.x * 64;

    f32x4 acc[4][8];
    #pragma unroll
    for (int m = 0; m < 4; ++m)
        #pragma unroll
        for (int n = 0; n < 8; ++n) acc[m][n] = (f32x4){0.f, 0.f, 0.f, 0.f};

    for (int kt = 0; kt < C_/32; ++kt) {
        const int k0 = kt * 32;
        __syncthreads();
        // stage A: 64x32 fp32 -> bf16 (512 float4 groups, 2/thread)
        #pragma unroll
        for (int i = 0; i < 2; ++i) {
            int g = tid + i*256;
            int r = g >> 3, c4 = g & 7;
            float4 v = *(const float4*)(att + (size_t)(row0 + r)*C_ + k0 + c4*4);
            ushort4 o; o.x = f2bf(v.x); o.y = f2bf(v.y); o.z = f2bf(v.z); o.w = f2bf(v.w);
            *(ushort4*)&lA[r*K2_LDK + c4*4] = o;
        }
        // stage B: 512x32 bf16 (2048 ushort8 groups, 8/thread)
        #pragma unroll
        for (int i = 0; i < 8; ++i) {
            int g = tid + i*256;
            int r = g >> 2, c8 = g & 3;
            uint4 v = *(const uint4*)(wa + (size_t)r*C_ + k0 + c8*8);
            *(uint4*)&lB[r*K2_LDK + c8*8] = v;
        }
        __syncthreads();

        bf16x8 af[4];
        #pragma unroll
        for (int m = 0; m < 4; ++m)
            af[m] = *(const bf16x8*)&lA[(m*16 + l16)*K2_LDK + lq*8];
        #pragma unroll
        for (int n = 0; n < 8; ++n) {
            bf16x8 bfr = *(const bf16x8*)&lB[(w*128 + n*16 + l16)*K2_LDK + lq*8];
            #pragma unroll
            for (int m = 0; m < 4; ++m)
                acc[m][n] = __builtin_amdgcn_mfma_f32_16x16x32_bf16(af[m], bfr, acc[m][n], 0, 0, 0);
        }
    }

    // epilogue: tanh + dot(Wo) + reduce
    #pragma unroll
    for (int m = 0; m < 4; ++m) {
        #pragma unroll
        for (int r = 0; r < 4; ++r) {
            int lrow = m*16 + lq*4 + r;
            int grow = row0 + lrow;
            int bidx = grow / L_;
            float s = 0.f;
            #pragma unroll
            for (int n = 0; n < 8; ++n) {
                int col = w*128 + n*16 + l16;
                float v = acc[m][n][r] + hlin[bidx*A_ + col];
                s += tanhf(v) * wo[col];
            }
            s += __shfl_xor(s, 1);
            s += __shfl_xor(s, 2);
            s += __shfl_xor(s, 4);
            s += __shfl_xor(s, 8);
            if (l16 == 0) red[w][lrow] = s;
        }
    }
    __syncthreads();
    if (tid < 64) {
        float tot = red[0][tid] + red[1][tid] + red[2][tid] + red[3][tid] + bo[0];
        scores[row0 + tid] = tot;
    }
}

// ---------------- softmax over L per batch ----------------
__global__ void k_softmax(const float* __restrict__ scores, float* __restrict__ cw) {
    __shared__ float sm[4], ss[4];
    int b = blockIdx.x, t = threadIdx.x, w = t >> 6, l = t & 63;
    float v = (t < L_) ? scores[b*L_ + t] : -1e30f;
    float m = v;
    #pragma unroll
    for (int o = 1; o < 64; o <<= 1) m = fmaxf(m, __shfl_xor(m, o));
    if (l == 0) sm[w] = m;
    __syncthreads();
    m = fmaxf(fmaxf(sm[0], sm[1]), fmaxf(sm[2], sm[3]));
    float e = (t < L_) ? expf(v - m) : 0.f;
    float s = e;
    #pragma unroll
    for (int o = 1; o < 64; o <<= 1) s += __shfl_xor(s, o);
    if (l == 0) ss[w] = s;
    __syncthreads();
    s = ss[0] + ss[1] + ss[2] + ss[3];
    if (t < L_) cw[b*L_ + t] = e / s;
}

// ---------------- z = sum_l cw[b][l]*att[b][l][:] -> xcat bf16 ----------------
__global__ void k_z(const float* __restrict__ att, const float* __restrict__ cw,
                    unsigned short* __restrict__ xcat) {
    __shared__ float w_s[L_];
    int b = blockIdx.y, half = blockIdx.x, t = threadIdx.x;
    if (t < L_) w_s[t] = cw[b*L_ + t];
    __syncthreads();
    int c = half*1024 + t*4;
    const float* base = att + (size_t)b*L_*C_ + c;
    float ax = 0.f, ay = 0.f, az = 0.f, aw = 0.f;
    #pragma unroll 4
    for (int li = 0; li < L_; ++li) {
        float4 v = *(const float4*)(base + (size_t)li*C_);
        float wt = w_s[li];
        ax += wt*v.x; ay += wt*v.y; az += wt*v.z; aw += wt*v.w;
    }
    ushort4 o; o.x = f2bf(ax); o.y = f2bf(ay); o.z = f2bf(az); o.w = f2bf(aw);
    *(ushort4*)(xcat + (size_t)b*3072 + 1024 + c) = o;
}

// ---------------- GEMM2: S = xcat @ wcat^T + bcat ----------------
// M=256, N=2048, K=3072; block 64x128, 4 waves (each 64x32)
__global__ __launch_bounds__(256) void k_gemm2(
    const unsigned short* __restrict__ xcat,  // [256][3072] bf16
    const unsigned short* __restrict__ wcat,  // [2048][3072] bf16
    const float* __restrict__ bcat,           // [2048]
    float* __restrict__ S)                    // [256][2048]
{
    __shared__ unsigned short lA[64 * K2_LDK];
    __shared__ unsigned short lB[128 * K2_LDK];
    const int tid = threadIdx.x;
    const int w = tid >> 6, l = tid & 63;
    const int l16 = l & 15, lq = l >> 4;
    const int row0 = blockIdx.y * 64;
    const int col0 = blockIdx.x * 128;

    f32x4 acc[4][2];
    #pragma unroll
    for (int m = 0; m < 4; ++m)
        #pragma unroll
        for (int n = 0; n < 2; ++n) acc[m][n] = (f32x4){0.f, 0.f, 0.f, 0.f};

    for (int kt = 0; kt < 3072/32; ++kt) {
        const int k0 = kt * 32;
        __syncthreads();
        {   // A: 64x32 (256 groups, 1/thread)
            int r = tid >> 2, c8 = tid & 3;
            *(uint4*)&lA[r*K2_LDK + c8*8] =
                *(const uint4*)(xcat + (size_t)(row0 + r)*3072 + k0 + c8*8);
        }
        #pragma unroll
        for (int i = 0; i < 2; ++i) {  // B: 128x32 (512 groups, 2/thread)
            int g = tid + i*256;
            int r = g >> 2, c8 = g & 3;
            *(uint4*)&lB[r*K2_LDK + c8*8] =
                *(const uint4*)(wcat + (size_t)(col0 + r)*3072 + k0 + c8*8);
        }
        __syncthreads();

        bf16x8 af[4];
        #pragma unroll
        for (int m = 0; m < 4; ++m)
            af[m] = *(const bf16x8*)&lA[(m*16 + l16)*K2_LDK + lq*8];
        #pragma unroll
        for (int n = 0; n < 2; ++n) {
            bf16x8 bfr = *(const bf16x8*)&lB[(w*32 + n*16 + l16)*K2_LDK + lq*8];
            #pragma unroll
            for (int m = 0; m < 4; ++m)
                acc[m][n] = __builtin_amdgcn_mfma_f32_16x16x32_bf16(af[m], bfr, acc[m][n], 0, 0, 0);
        }
    }

    #pragma unroll
    for (int m = 0; m < 4; ++m)
        #pragma unroll
        for (int n = 0; n < 2; ++n)
            #pragma unroll
            for (int r = 0; r < 4; ++r) {
                int grow = row0 + m*16 + lq*4 + r;
                int col = col0 + w*32 + n*16 + l16;
                S[(size_t)grow*2048 + col] = acc[m][n][r] + bcat[col];
            }
}

// ---------------- LSTM gates ----------------
__global__ void k_lstm(const float* __restrict__ S, const float* __restrict__ prec,
                       float* __restrict__ out) {
    int b = blockIdx.x, h = threadIdx.x;  // 512 threads
    float ig = 1.f / (1.f + expf(-S[(size_t)b*2048 + h]));
    float fg = 1.f / (1.f + expf(-S[(size_t)b*2048 + 512 + h]));
    float og = 1.f / (1.f + expf(-S[(size_t)b*2048 + 1024 + h]));
    float gt = tanhf(S[(size_t)b*2048 + 1536 + h]);
    float c = fg * prec[b*512 + h] + ig * gt;
    out[b*512 + h] = og * tanhf(c);
    out[131072 + b*512 + h] = c;
}

// ---------------- launch ----------------
extern "C" void kernel_launch(void* const* d_in, const int* in_sizes, int n_in,
                              void* d_out, int out_size, void* d_ws, size_t ws_size,
                              hipStream_t stream) {
    const float* xt  = (const float*)d_in[0];
    const float* att = (const float*)d_in[1];
    const float* h0  = (const float*)d_in[2];
    const float* c0  = (const float*)d_in[3];
    const float* Wi  = (const float*)d_in[4];
    const float* bi  = (const float*)d_in[5];
    const float* Wh  = (const float*)d_in[6];
    const float* bh  = (const float*)d_in[7];
    const float* Wz  = (const float*)d_in[8];
    const float* bz  = (const float*)d_in[9];
    const float* Wa  = (const float*)d_in[10];
    const float* ba  = (const float*)d_in[11];
    const float* Wha = (const float*)d_in[12];
    const float* bha = (const float*)d_in[13];
    const float* Wo  = (const float*)d_in[14];
    const float* bo  = (const float*)d_in[15];
    float* out = (float*)d_out;

    char* ws = (char*)d_ws;
    unsigned short* wa_bf   = (unsigned short*)(ws);                       // 2 MB
    unsigned short* wcat_bf = (unsigned short*)(ws + 2097152);             // 12 MB
    unsigned short* xcat_bf = (unsigned short*)(ws + 14680064);            // 1.5 MB
    float* hlin   = (float*)(ws + 16252928);                               // 512 KB
    float* scores = (float*)(ws + 16777216);                               // 200 KB
    float* cw     = (float*)(ws + 16977920);                               // 200 KB
    float* bcat   = (float*)(ws + 17178624);                               // 8 KB
    float* S      = (float*)(ws + 17186816);                               // 2 MB

    k_cvt<<<1024, 256, 0, stream>>>(Wa, wa_bf, 262144);
    k_build_wcat<<<2048, 256, 0, stream>>>(Wi, Wh, Wz, bi, bh, bz, wcat_bf, bcat);
    k_build_xcat<<<256, 256, 0, stream>>>(xt, h0, xcat_bf);
    k_hlin<<<256, 512, 0, stream>>>(h0, Wha, bha, ba, hlin);
    k_scores<<<M_/64, 256, 0, stream>>>(att, wa_bf, hlin, Wo, bo, scores);
    k_softmax<<<256, 256, 0, stream>>>(scores, cw);
    k_z<<<dim3(2, 256), 256, 0, stream>>>(att, cw, xcat_bf);
    k_gemm2<<<dim3(16, 4), 256, 0, stream>>>(xcat_bf, wcat_bf, bcat, S);
    k_lstm<<<256, 512, 0, stream>>>(S, c0, out);
}

// Round 3
// 446.101 us; speedup vs baseline: 1.0022x; 1.0014x over previous
//
#include <hip/hip_runtime.h>
#include <stdint.h>

#define B_ 256
#define L_ 196
#define C_ 2048
#define E_ 512
#define H_ 512
#define A_ 512
#define M_ (B_*L_)   // 50176

typedef __bf16 bf16x8 __attribute__((ext_vector_type(8)));
typedef float  f32x4  __attribute__((ext_vector_type(4)));

__device__ __forceinline__ unsigned short f2bf(float f) {
    union { float f; unsigned int u; } v; v.f = f;
    unsigned int r = 0x7FFFu + ((v.u >> 16) & 1u);
    return (unsigned short)((v.u + r) >> 16);
}

// ---------------- prep kernels ----------------

__global__ void k_cvt(const float* __restrict__ src, unsigned short* __restrict__ dst, int n4) {
    int i = blockIdx.x * blockDim.x + threadIdx.x;
    if (i < n4) {
        float4 v = ((const float4*)src)[i];
        ushort4 o; o.x = f2bf(v.x); o.y = f2bf(v.y); o.z = f2bf(v.z); o.w = f2bf(v.w);
        ((ushort4*)dst)[i] = o;
    }
}

// wcat[j][0:512]=Wi[j], [512:1024]=Wh[j], [1024:3072]=Wz[j]; bcat[j]=bi+bh+bz
__global__ void k_build_wcat(const float* __restrict__ Wi, const float* __restrict__ Wh,
                             const float* __restrict__ Wz, const float* __restrict__ bi,
                             const float* __restrict__ bh, const float* __restrict__ bz,
                             unsigned short* __restrict__ wcat, float* __restrict__ bcat) {
    int j = blockIdx.x;       // 2048
    int t = threadIdx.x;      // 256
    for (int g = t; g < 768; g += 256) {
        int k = g * 4;
        const float* src;
        if (k < 512)       src = Wi + j*512 + k;
        else if (k < 1024) src = Wh + j*512 + (k - 512);
        else               src = Wz + j*2048 + (k - 1024);
        float4 v = *(const float4*)src;
        ushort4 o; o.x = f2bf(v.x); o.y = f2bf(v.y); o.z = f2bf(v.z); o.w = f2bf(v.w);
        *(ushort4*)(wcat + (size_t)j*3072 + k) = o;
    }
    if (t == 0) bcat[j] = bi[j] + bh[j] + bz[j];
}

// xcat[b][0:512]=xt[b], [512:1024]=pre_h[b]  (z part written by k_z)
__global__ void k_build_xcat(const float* __restrict__ xt, const float* __restrict__ preh,
                             unsigned short* __restrict__ xcat) {
    int b = blockIdx.x, t = threadIdx.x;  // 256 threads
    const float* src = (t < 128) ? (xt + b*512 + t*4) : (preh + b*512 + (t-128)*4);
    int off = (t < 128) ? (t*4) : (512 + (t-128)*4);
    float4 v = *(const float4*)src;
    ushort4 o; o.x = f2bf(v.x); o.y = f2bf(v.y); o.z = f2bf(v.z); o.w = f2bf(v.w);
    *(ushort4*)(xcat + (size_t)b*3072 + off) = o;
}

// hlin[b][a] = pre_h[b]·Wha[a] + bha[a] + ba[a]   (ba folded in)
__global__ void k_hlin(const float* __restrict__ preh, const float* __restrict__ Wha,
                       const float* __restrict__ bha, const float* __restrict__ ba,
                       float* __restrict__ hlin) {
    __shared__ float ph[512];
    int b = blockIdx.x, t = threadIdx.x;   // 512 threads
    ph[t] = preh[b*512 + t];
    __syncthreads();
    float acc = bha[t] + ba[t];
    const float4* wrow = (const float4*)(Wha + (size_t)t*512);
    #pragma unroll 8
    for (int k4 = 0; k4 < 128; ++k4) {
        float4 v = wrow[k4];
        float4 p = *(const float4*)&ph[k4*4];
        acc += v.x*p.x + v.y*p.y + v.z*p.z + v.w*p.w;
    }
    hlin[b*512 + t] = acc;
}

// ---------------- fused scores GEMM ----------------
// scores[row] = bo + sum_a Wo[a] * tanh( att[row]·Wa[a] + hlin[b(row)][a] )
// block: 64 rows x all 512 cols, K=2048, BK=32, 4 waves (each 64x128)
#define K2_LDK 40

__global__ __launch_bounds__(256, 2) void k_scores(
    const float* __restrict__ att,          // [M_][C_] fp32
    const unsigned short* __restrict__ wa,  // [A_][C_] bf16
    const float* __restrict__ hlin,         // [B_][A_]
    const float* __restrict__ wo,           // [A_]
    const float* __restrict__ bo,           // [1]
    float* __restrict__ scores)             // [M_]
{
    __shared__ unsigned short lA[64 * K2_LDK];
    __shared__ unsigned short lB[512 * K2_LDK];
    __shared__ float red[4][64];

    const int tid = threadIdx.x;
    const int w = tid >> 6, l = tid & 63;
    const int l16 = l & 15, lq = l >> 4;
    const int row0 = blockIdx.x * 64;

    f32x4 acc[4][8];
    #pragma unroll
    for (int m = 0; m < 4; ++m)
        #pragma unroll
        for (int n = 0; n < 8; ++n) acc[m][n] = (f32x4){0.f, 0.f, 0.f, 0.f};

    for (int kt = 0; kt < C_/32; ++kt) {
        const int k0 = kt * 32;
        __syncthreads();
        // stage A: 64x32 fp32 -> bf16 (512 float4 groups, 2/thread)
        #pragma unroll
        for (int i = 0; i < 2; ++i) {
            int g = tid + i*256;
            int r = g >> 3, c4 = g & 7;
            float4 v = *(const float4*)(att + (size_t)(row0 + r)*C_ + k0 + c4*4);
            ushort4 o; o.x = f2bf(v.x); o.y = f2bf(v.y); o.z = f2bf(v.z); o.w = f2bf(v.w);
            *(ushort4*)&lA[r*K2_LDK + c4*4] = o;
        }
        // stage B: 512x32 bf16 (2048 ushort8 groups, 8/thread)
        #pragma unroll
        for (int i = 0; i < 8; ++i) {
            int g = tid + i*256;
            int r = g >> 2, c8 = g & 3;
            uint4 v = *(const uint4*)(wa + (size_t)r*C_ + k0 + c8*8);
            *(uint4*)&lB[r*K2_LDK + c8*8] = v;
        }
        __syncthreads();

        bf16x8 af[4];
        #pragma unroll
        for (int m = 0; m < 4; ++m)
            af[m] = *(const bf16x8*)&lA[(m*16 + l16)*K2_LDK + lq*8];
        #pragma unroll
        for (int n = 0; n < 8; ++n) {
            bf16x8 bfr = *(const bf16x8*)&lB[(w*128 + n*16 + l16)*K2_LDK + lq*8];
            #pragma unroll
            for (int m = 0; m < 4; ++m)
                acc[m][n] = __builtin_amdgcn_mfma_f32_16x16x32_bf16(af[m], bfr, acc[m][n], 0, 0, 0);
        }
    }

    // epilogue: tanh + dot(Wo) + reduce
    #pragma unroll
    for (int m = 0; m < 4; ++m) {
        #pragma unroll
        for (int r = 0; r < 4; ++r) {
            int lrow = m*16 + lq*4 + r;
            int grow = row0 + lrow;
            int bidx = grow / L_;
            float s = 0.f;
            #pragma unroll
            for (int n = 0; n < 8; ++n) {
                int col = w*128 + n*16 + l16;
                float v = acc[m][n][r] + hlin[bidx*A_ + col];
                s += tanhf(v) * wo[col];
            }
            s += __shfl_xor(s, 1);
            s += __shfl_xor(s, 2);
            s += __shfl_xor(s, 4);
            s += __shfl_xor(s, 8);
            if (l16 == 0) red[w][lrow] = s;
        }
    }
    __syncthreads();
    if (tid < 64) {
        float tot = red[0][tid] + red[1][tid] + red[2][tid] + red[3][tid] + bo[0];
        scores[row0 + tid] = tot;
    }
}

// ---------------- softmax over L per batch ----------------
__global__ void k_softmax(const float* __restrict__ scores, float* __restrict__ cw) {
    __shared__ float sm[4], ss[4];
    int b = blockIdx.x, t = threadIdx.x, w = t >> 6, l = t & 63;
    float v = (t < L_) ? scores[b*L_ + t] : -1e30f;
    float m = v;
    #pragma unroll
    for (int o = 1; o < 64; o <<= 1) m = fmaxf(m, __shfl_xor(m, o));
    if (l == 0) sm[w] = m;
    __syncthreads();
    m = fmaxf(fmaxf(sm[0], sm[1]), fmaxf(sm[2], sm[3]));
    float e = (t < L_) ? expf(v - m) : 0.f;
    float s = e;
    #pragma unroll
    for (int o = 1; o < 64; o <<= 1) s += __shfl_xor(s, o);
    if (l == 0) ss[w] = s;
    __syncthreads();
    s = ss[0] + ss[1] + ss[2] + ss[3];
    if (t < L_) cw[b*L_ + t] = e / s;
}

// ---------------- z = sum_l cw[b][l]*att[b][l][:] -> xcat bf16 ----------------
__global__ void k_z(const float* __restrict__ att, const float* __restrict__ cw,
                    unsigned short* __restrict__ xcat) {
    __shared__ float w_s[L_];
    int b = blockIdx.y, half = blockIdx.x, t = threadIdx.x;
    if (t < L_) w_s[t] = cw[b*L_ + t];
    __syncthreads();
    int c = half*1024 + t*4;
    const float* base = att + (size_t)b*L_*C_ + c;
    float ax = 0.f, ay = 0.f, az = 0.f, aw = 0.f;
    #pragma unroll 4
    for (int li = 0; li < L_; ++li) {
        float4 v = *(const float4*)(base + (size_t)li*C_);
        float wt = w_s[li];
        ax += wt*v.x; ay += wt*v.y; az += wt*v.z; aw += wt*v.w;
    }
    ushort4 o; o.x = f2bf(ax); o.y = f2bf(ay); o.z = f2bf(az); o.w = f2bf(aw);
    *(ushort4*)(xcat + (size_t)b*3072 + 1024 + c) = o;
}

// ---------------- GEMM2: S = xcat @ wcat^T + bcat ----------------
// M=256, N=2048, K=3072; block 64x128, 4 waves (each 64x32)
__global__ __launch_bounds__(256) void k_gemm2(
    const unsigned short* __restrict__ xcat,  // [256][3072] bf16
    const unsigned short* __restrict__ wcat,  // [2048][3072] bf16
    const float* __restrict__ bcat,           // [2048]
    float* __restrict__ S)                    // [256][2048]
{
    __shared__ unsigned short lA[64 * K2_LDK];
    __shared__ unsigned short lB[128 * K2_LDK];
    const int tid = threadIdx.x;
    const int w = tid >> 6, l = tid & 63;
    const int l16 = l & 15, lq = l >> 4;
    const int row0 = blockIdx.y * 64;
    const int col0 = blockIdx.x * 128;

    f32x4 acc[4][2];
    #pragma unroll
    for (int m = 0; m < 4; ++m)
        #pragma unroll
        for (int n = 0; n < 2; ++n) acc[m][n] = (f32x4){0.f, 0.f, 0.f, 0.f};

    for (int kt = 0; kt < 3072/32; ++kt) {
        const int k0 = kt * 32;
        __syncthreads();
        {   // A: 64x32 (256 groups, 1/thread)
            int r = tid >> 2, c8 = tid & 3;
            *(uint4*)&lA[r*K2_LDK + c8*8] =
                *(const uint4*)(xcat + (size_t)(row0 + r)*3072 + k0 + c8*8);
        }
        #pragma unroll
        for (int i = 0; i < 2; ++i) {  // B: 128x32 (512 groups, 2/thread)
            int g = tid + i*256;
            int r = g >> 2, c8 = g & 3;
            *(uint4*)&lB[r*K2_LDK + c8*8] =
                *(const uint4*)(wcat + (size_t)(col0 + r)*3072 + k0 + c8*8);
        }
        __syncthreads();

        bf16x8 af[4];
        #pragma unroll
        for (int m = 0; m < 4; ++m)
            af[m] = *(const bf16x8*)&lA[(m*16 + l16)*K2_LDK + lq*8];
        #pragma unroll
        for (int n = 0; n < 2; ++n) {
            bf16x8 bfr = *(const bf16x8*)&lB[(w*32 + n*16 + l16)*K2_LDK + lq*8];
            #pragma unroll
            for (int m = 0; m < 4; ++m)
                acc[m][n] = __builtin_amdgcn_mfma_f32_16x16x32_bf16(af[m], bfr, acc[m][n], 0, 0, 0);
        }
    }

    #pragma unroll
    for (int m = 0; m < 4; ++m)
        #pragma unroll
        for (int n = 0; n < 2; ++n)
            #pragma unroll
            for (int r = 0; r < 4; ++r) {
                int grow = row0 + m*16 + lq*4 + r;
                int col = col0 + w*32 + n*16 + l16;
                S[(size_t)grow*2048 + col] = acc[m][n][r] + bcat[col];
            }
}

// ---------------- LSTM gates ----------------
__global__ void k_lstm(const float* __restrict__ S, const float* __restrict__ prec,
                       float* __restrict__ out) {
    int b = blockIdx.x, h = threadIdx.x;  // 512 threads
    float ig = 1.f / (1.f + expf(-S[(size_t)b*2048 + h]));
    float fg = 1.f / (1.f + expf(-S[(size_t)b*2048 + 512 + h]));
    float og = 1.f / (1.f + expf(-S[(size_t)b*2048 + 1024 + h]));
    float gt = tanhf(S[(size_t)b*2048 + 1536 + h]);
    float c = fg * prec[b*512 + h] + ig * gt;
    out[b*512 + h] = og * tanhf(c);
    out[131072 + b*512 + h] = c;
}

// ---------------- launch ----------------
extern "C" void kernel_launch(void* const* d_in, const int* in_sizes, int n_in,
                              void* d_out, int out_size, void* d_ws, size_t ws_size,
                              hipStream_t stream) {
    const float* xt  = (const float*)d_in[0];
    const float* att = (const float*)d_in[1];
    const float* h0  = (const float*)d_in[2];
    const float* c0  = (const float*)d_in[3];
    const float* Wi  = (const float*)d_in[4];
    const float* bi  = (const float*)d_in[5];
    const float* Wh  = (const float*)d_in[6];
    const float* bh  = (const float*)d_in[7];
    const float* Wz  = (const float*)d_in[8];
    const float* bz  = (const float*)d_in[9];
    const float* Wa  = (const float*)d_in[10];
    const float* ba  = (const float*)d_in[11];
    const float* Wha = (const float*)d_in[12];
    const float* bha = (const float*)d_in[13];
    const float* Wo  = (const float*)d_in[14];
    const float* bo  = (const float*)d_in[15];
    float* out = (float*)d_out;

    char* ws = (char*)d_ws;
    unsigned short* wa_bf   = (unsigned short*)(ws);                       // 2 MB
    unsigned short* wcat_bf = (unsigned short*)(ws + 2097152);             // 12 MB
    unsigned short* xcat_bf = (unsigned short*)(ws + 14680064);            // 1.5 MB
    float* hlin   = (float*)(ws + 16252928);                               // 512 KB
    float* scores = (float*)(ws + 16777216);                               // 200 KB
    float* cw     = (float*)(ws + 16977920);                               // 200 KB
    float* bcat   = (float*)(ws + 17178624);                               // 8 KB
    float* S      = (float*)(ws + 17186816);                               // 2 MB

    k_cvt<<<1024, 256, 0, stream>>>(Wa, wa_bf, 262144);
    k_build_wcat<<<2048, 256, 0, stream>>>(Wi, Wh, Wz, bi, bh, bz, wcat_bf, bcat);
    k_build_xcat<<<256, 256, 0, stream>>>(xt, h0, xcat_bf);
    k_hlin<<<256, 512, 0, stream>>>(h0, Wha, bha, ba, hlin);
    k_scores<<<M_/64, 256, 0, stream>>>(att, wa_bf, hlin, Wo, bo, scores);
    k_softmax<<<256, 256, 0, stream>>>(scores, cw);
    k_z<<<dim3(2, 256), 256, 0, stream>>>(att, cw, xcat_bf);
    k_gemm2<<<dim3(16, 4), 256, 0, stream>>>(xcat_bf, wcat_bf, bcat, S);
    k_lstm<<<256, 512, 0, stream>>>(S, c0, out);
}

// Round 4
// 396.854 us; speedup vs baseline: 1.1265x; 1.1241x over previous
//
#include <hip/hip_runtime.h>
#include <stdint.h>

#define B_ 256
#define L_ 196
#define C_ 2048
#define E_ 512
#define H_ 512
#define A_ 512
#define M_ (B_*L_)   // 50176

typedef __bf16 bf16x8 __attribute__((ext_vector_type(8)));
typedef float  f32x4  __attribute__((ext_vector_type(4)));

__device__ __forceinline__ unsigned short f2bf(float f) {
    union { float f; unsigned int u; } v; v.f = f;
    unsigned int r = 0x7FFFu + ((v.u >> 16) & 1u);
    return (unsigned short)((v.u + r) >> 16);
}

__device__ __forceinline__ unsigned int pk2(float a, float b) {
    return (unsigned int)f2bf(a) | ((unsigned int)f2bf(b) << 16);
}

__device__ __forceinline__ float tanh_fast(float x) {
    float e = __expf(2.f * x);          // inf-safe: e=inf -> 1; e=0 -> -1
    return 1.f - 2.f / (e + 1.f);
}

__device__ __forceinline__ void gload_lds16(const void* g, void* s) {
    __builtin_amdgcn_global_load_lds(
        (const __attribute__((address_space(1))) void*)g,
        (__attribute__((address_space(3))) void*)s, 16, 0, 0);
}

// ---------------- prep kernels ----------------

__global__ void k_cvt(const float* __restrict__ src, unsigned short* __restrict__ dst, int n4) {
    int i = blockIdx.x * blockDim.x + threadIdx.x;
    if (i < n4) {
        float4 v = ((const float4*)src)[i];
        ushort4 o; o.x = f2bf(v.x); o.y = f2bf(v.y); o.z = f2bf(v.z); o.w = f2bf(v.w);
        ((ushort4*)dst)[i] = o;
    }
}

__global__ void k_build_wcat(const float* __restrict__ Wi, const float* __restrict__ Wh,
                             const float* __restrict__ Wz, const float* __restrict__ bi,
                             const float* __restrict__ bh, const float* __restrict__ bz,
                             unsigned short* __restrict__ wcat, float* __restrict__ bcat) {
    int j = blockIdx.x;       // 2048
    int t = threadIdx.x;      // 256
    for (int g = t; g < 768; g += 256) {
        int k = g * 4;
        const float* src;
        if (k < 512)       src = Wi + j*512 + k;
        else if (k < 1024) src = Wh + j*512 + (k - 512);
        else               src = Wz + j*2048 + (k - 1024);
        float4 v = *(const float4*)src;
        ushort4 o; o.x = f2bf(v.x); o.y = f2bf(v.y); o.z = f2bf(v.z); o.w = f2bf(v.w);
        *(ushort4*)(wcat + (size_t)j*3072 + k) = o;
    }
    if (t == 0) bcat[j] = bi[j] + bh[j] + bz[j];
}

__global__ void k_build_xcat(const float* __restrict__ xt, const float* __restrict__ preh,
                             unsigned short* __restrict__ xcat) {
    int b = blockIdx.x, t = threadIdx.x;  // 256 threads
    const float* src = (t < 128) ? (xt + b*512 + t*4) : (preh + b*512 + (t-128)*4);
    int off = (t < 128) ? (t*4) : (512 + (t-128)*4);
    float4 v = *(const float4*)src;
    ushort4 o; o.x = f2bf(v.x); o.y = f2bf(v.y); o.z = f2bf(v.z); o.w = f2bf(v.w);
    *(ushort4*)(xcat + (size_t)b*3072 + off) = o;
}

__global__ void k_hlin(const float* __restrict__ preh, const float* __restrict__ Wha,
                       const float* __restrict__ bha, const float* __restrict__ ba,
                       float* __restrict__ hlin) {
    __shared__ float ph[512];
    int b = blockIdx.x, t = threadIdx.x;   // 512 threads
    ph[t] = preh[b*512 + t];
    __syncthreads();
    float acc = bha[t] + ba[t];
    const float4* wrow = (const float4*)(Wha + (size_t)t*512);
    #pragma unroll 8
    for (int k4 = 0; k4 < 128; ++k4) {
        float4 v = wrow[k4];
        float4 p = *(const float4*)&ph[k4*4];
        acc += v.x*p.x + v.y*p.y + v.z*p.z + v.w*p.w;
    }
    hlin[b*512 + t] = acc;
}

// ---------------- fused scores GEMM ----------------
// scores[row] = bo + sum_a Wo[a] * tanh( att[row]·Wa[a] + hlin[b(row)][a] )
// Block: 128 rows x all 512 cols, K=2048, BK=64, 512 threads (8 waves, 2x4).
// LDS: lA 128x64 bf16 (16 KB) + lB 512x64 bf16 (64 KB) = exactly 80 KB.
// Both tiles XOR-chunk-swizzled: 16B chunk p of row r holds logical chunk p^(r&7).
// lB staged via global_load_lds (linear dest) with pre-swizzled global source.

__global__ __launch_bounds__(512, 2) void k_scores(
    const float* __restrict__ att,          // [M_][C_] fp32
    const unsigned short* __restrict__ wa,  // [A_][C_] bf16
    const float* __restrict__ hlin,         // [B_][A_]
    const float* __restrict__ wo,           // [A_]
    const float* __restrict__ bo,           // [1]
    float* __restrict__ scores)             // [M_]
{
    __shared__ unsigned short smem[40960];  // 81920 B
    unsigned short* lA = smem;              // 128*64
    unsigned short* lB = smem + 128*64;     // 512*64

    const int tid = threadIdx.x;
    const int w = tid >> 6, l = tid & 63;
    const int l16 = l & 15, lq = l >> 4;
    const int wr = w >> 2, wc = w & 3;      // wave tile: rows wr*64, cols wc*128
    const int row0 = blockIdx.x * 128;

    // A staging assignment: thread t -> local row t>>2, logical chunks pp, pp+1
    const int ar = tid >> 2;
    const int app = (tid & 3) * 2;

    f32x4 acc[4][8];
    #pragma unroll
    for (int m = 0; m < 4; ++m)
        #pragma unroll
        for (int n = 0; n < 8; ++n) acc[m][n] = (f32x4){0.f, 0.f, 0.f, 0.f};

    for (int kt = 0; kt < C_/64; ++kt) {
        const int k0 = kt * 64;
        __syncthreads();

        // --- B: 512x64 bf16 via global_load_lds, linear LDS dest, swizzled src
        #pragma unroll
        for (int i = 0; i < 8; ++i) {
            int g = w*64 + l + i*512;           // chunk id 0..4095
            int br = g >> 3, bp = g & 7;
            int bps = bp ^ (br & 7);            // pre-swizzled source chunk
            gload_lds16(wa + (size_t)br*C_ + k0 + bps*8,
                        lB + (size_t)(w*64 + i*512)*8);
        }

        // --- A: 128x64 fp32 -> bf16, reg-staged, swizzled ds_write_b128
        {
            const float* ga = att + (size_t)(row0 + ar)*C_ + k0 + app*8;
            float4 v0 = *(const float4*)(ga);
            float4 v1 = *(const float4*)(ga + 4);
            float4 v2 = *(const float4*)(ga + 8);
            float4 v3 = *(const float4*)(ga + 12);
            uint4 w0 = make_uint4(pk2(v0.x,v0.y), pk2(v0.z,v0.w), pk2(v1.x,v1.y), pk2(v1.z,v1.w));
            uint4 w1 = make_uint4(pk2(v2.x,v2.y), pk2(v2.z,v2.w), pk2(v3.x,v3.y), pk2(v3.z,v3.w));
            int rs = ar & 7;
            *(uint4*)&lA[ar*64 + ((app     ^ rs) * 8)] = w0;
            *(uint4*)&lA[ar*64 + (((app+1) ^ rs) * 8)] = w1;
        }
        __syncthreads();

        // --- compute: 2 k-sub-steps of 32
        #pragma unroll
        for (int kk = 0; kk < 2; ++kk) {
            bf16x8 af[4];
            #pragma unroll
            for (int m = 0; m < 4; ++m) {
                int rrow = wr*64 + m*16 + l16;
                int c = kk*4 + lq;
                af[m] = *(const bf16x8*)&lA[rrow*64 + ((c ^ (rrow & 7)) * 8)];
            }
            #pragma unroll
            for (int n = 0; n < 8; ++n) {
                int brow = wc*128 + n*16 + l16;
                int c = kk*4 + lq;
                bf16x8 bfr = *(const bf16x8*)&lB[brow*64 + ((c ^ (brow & 7)) * 8)];
                #pragma unroll
                for (int m = 0; m < 4; ++m)
                    acc[m][n] = __builtin_amdgcn_mfma_f32_16x16x32_bf16(af[m], bfr, acc[m][n], 0, 0, 0);
            }
        }
    }

    __syncthreads();                 // all LDS reads done; safe to alias red
    float* red = (float*)smem;       // [4 wc][128 rows]

    // epilogue: tanh + dot(Wo) + reduce
    const int colbase = wc*128 + l16;
    float won[8], hlA[8], hlB[8];
    const int bA = row0 / L_;
    const int bB = (row0 + 127) / L_;
    const int rsplit = (bA + 1) * L_;
    #pragma unroll
    for (int n = 0; n < 8; ++n) {
        won[n] = wo[colbase + n*16];
        hlA[n] = hlin[bA*A_ + colbase + n*16];
        hlB[n] = hlin[bB*A_ + colbase + n*16];
    }

    #pragma unroll
    for (int m = 0; m < 4; ++m) {
        #pragma unroll
        for (int r = 0; r < 4; ++r) {
            int lrow = wr*64 + m*16 + lq*4 + r;
            int grow = row0 + lrow;
            bool useB = grow >= rsplit;
            float s = 0.f;
            #pragma unroll
            for (int n = 0; n < 8; ++n) {
                float v = acc[m][n][r] + (useB ? hlB[n] : hlA[n]);
                s += tanh_fast(v) * won[n];
            }
            s += __shfl_xor(s, 1);
            s += __shfl_xor(s, 2);
            s += __shfl_xor(s, 4);
            s += __shfl_xor(s, 8);
            if (l16 == 0) red[wc*128 + lrow] = s;
        }
    }
    __syncthreads();
    if (tid < 128) {
        scores[row0 + tid] = red[tid] + red[128 + tid] + red[256 + tid] + red[384 + tid] + bo[0];
    }
}

// ---------------- softmax over L per batch ----------------
__global__ void k_softmax(const float* __restrict__ scores, float* __restrict__ cw) {
    __shared__ float sm[4], ss[4];
    int b = blockIdx.x, t = threadIdx.x, w = t >> 6, l = t & 63;
    float v = (t < L_) ? scores[b*L_ + t] : -1e30f;
    float m = v;
    #pragma unroll
    for (int o = 1; o < 64; o <<= 1) m = fmaxf(m, __shfl_xor(m, o));
    if (l == 0) sm[w] = m;
    __syncthreads();
    m = fmaxf(fmaxf(sm[0], sm[1]), fmaxf(sm[2], sm[3]));
    float e = (t < L_) ? expf(v - m) : 0.f;
    float s = e;
    #pragma unroll
    for (int o = 1; o < 64; o <<= 1) s += __shfl_xor(s, o);
    if (l == 0) ss[w] = s;
    __syncthreads();
    s = ss[0] + ss[1] + ss[2] + ss[3];
    if (t < L_) cw[b*L_ + t] = e / s;
}

// ---------------- z = sum_l cw[b][l]*att[b][l][:] -> xcat bf16 ----------------
__global__ void k_z(const float* __restrict__ att, const float* __restrict__ cw,
                    unsigned short* __restrict__ xcat) {
    __shared__ float w_s[L_];
    int b = blockIdx.y, half = blockIdx.x, t = threadIdx.x;
    if (t < L_) w_s[t] = cw[b*L_ + t];
    __syncthreads();
    int c = half*1024 + t*4;
    const float* base = att + (size_t)b*L_*C_ + c;
    float ax = 0.f, ay = 0.f, az = 0.f, aw = 0.f;
    #pragma unroll 4
    for (int li = 0; li < L_; ++li) {
        float4 v = *(const float4*)(base + (size_t)li*C_);
        float wt = w_s[li];
        ax += wt*v.x; ay += wt*v.y; az += wt*v.z; aw += wt*v.w;
    }
    ushort4 o; o.x = f2bf(ax); o.y = f2bf(ay); o.z = f2bf(az); o.w = f2bf(aw);
    *(ushort4*)(xcat + (size_t)b*3072 + 1024 + c) = o;
}

// ---------------- GEMM2: S = xcat @ wcat^T + bcat ----------------
#define K2_LDK 40
__global__ __launch_bounds__(256) void k_gemm2(
    const unsigned short* __restrict__ xcat,  // [256][3072] bf16
    const unsigned short* __restrict__ wcat,  // [2048][3072] bf16
    const float* __restrict__ bcat,           // [2048]
    float* __restrict__ S)                    // [256][2048]
{
    __shared__ unsigned short lA[64 * K2_LDK];
    __shared__ unsigned short lB[128 * K2_LDK];
    const int tid = threadIdx.x;
    const int w = tid >> 6, l = tid & 63;
    const int l16 = l & 15, lq = l >> 4;
    const int row0 = blockIdx.y * 64;
    const int col0 = blockIdx.x * 128;

    f32x4 acc[4][2];
    #pragma unroll
    for (int m = 0; m < 4; ++m)
        #pragma unroll
        for (int n = 0; n < 2; ++n) acc[m][n] = (f32x4){0.f, 0.f, 0.f, 0.f};

    for (int kt = 0; kt < 3072/32; ++kt) {
        const int k0 = kt * 32;
        __syncthreads();
        {
            int r = tid >> 2, c8 = tid & 3;
            *(uint4*)&lA[r*K2_LDK + c8*8] =
                *(const uint4*)(xcat + (size_t)(row0 + r)*3072 + k0 + c8*8);
        }
        #pragma unroll
        for (int i = 0; i < 2; ++i) {
            int g = tid + i*256;
            int r = g >> 2, c8 = g & 3;
            *(uint4*)&lB[r*K2_LDK + c8*8] =
                *(const uint4*)(wcat + (size_t)(col0 + r)*3072 + k0 + c8*8);
        }
        __syncthreads();

        bf16x8 af[4];
        #pragma unroll
        for (int m = 0; m < 4; ++m)
            af[m] = *(const bf16x8*)&lA[(m*16 + l16)*K2_LDK + lq*8];
        #pragma unroll
        for (int n = 0; n < 2; ++n) {
            bf16x8 bfr = *(const bf16x8*)&lB[(w*32 + n*16 + l16)*K2_LDK + lq*8];
            #pragma unroll
            for (int m = 0; m < 4; ++m)
                acc[m][n] = __builtin_amdgcn_mfma_f32_16x16x32_bf16(af[m], bfr, acc[m][n], 0, 0, 0);
        }
    }

    #pragma unroll
    for (int m = 0; m < 4; ++m)
        #pragma unroll
        for (int n = 0; n < 2; ++n)
            #pragma unroll
            for (int r = 0; r < 4; ++r) {
                int grow = row0 + m*16 + lq*4 + r;
                int col = col0 + w*32 + n*16 + l16;
                S[(size_t)grow*2048 + col] = acc[m][n][r] + bcat[col];
            }
}

// ---------------- LSTM gates ----------------
__global__ void k_lstm(const float* __restrict__ S, const float* __restrict__ prec,
                       float* __restrict__ out) {
    int b = blockIdx.x, h = threadIdx.x;  // 512 threads
    float ig = 1.f / (1.f + expf(-S[(size_t)b*2048 + h]));
    float fg = 1.f / (1.f + expf(-S[(size_t)b*2048 + 512 + h]));
    float og = 1.f / (1.f + expf(-S[(size_t)b*2048 + 1024 + h]));
    float gt = tanhf(S[(size_t)b*2048 + 1536 + h]);
    float c = fg * prec[b*512 + h] + ig * gt;
    out[b*512 + h] = og * tanhf(c);
    out[131072 + b*512 + h] = c;
}

// ---------------- launch ----------------
extern "C" void kernel_launch(void* const* d_in, const int* in_sizes, int n_in,
                              void* d_out, int out_size, void* d_ws, size_t ws_size,
                              hipStream_t stream) {
    const float* xt  = (const float*)d_in[0];
    const float* att = (const float*)d_in[1];
    const float* h0  = (const float*)d_in[2];
    const float* c0  = (const float*)d_in[3];
    const float* Wi  = (const float*)d_in[4];
    const float* bi  = (const float*)d_in[5];
    const float* Wh  = (const float*)d_in[6];
    const float* bh  = (const float*)d_in[7];
    const float* Wz  = (const float*)d_in[8];
    const float* bz  = (const float*)d_in[9];
    const float* Wa  = (const float*)d_in[10];
    const float* ba  = (const float*)d_in[11];
    const float* Wha = (const float*)d_in[12];
    const float* bha = (const float*)d_in[13];
    const float* Wo  = (const float*)d_in[14];
    const float* bo  = (const float*)d_in[15];
    float* out = (float*)d_out;

    char* ws = (char*)d_ws;
    unsigned short* wa_bf   = (unsigned short*)(ws);                       // 2 MB
    unsigned short* wcat_bf = (unsigned short*)(ws + 2097152);             // 12 MB
    unsigned short* xcat_bf = (unsigned short*)(ws + 14680064);            // 1.5 MB
    float* hlin   = (float*)(ws + 16252928);                               // 512 KB
    float* scores = (float*)(ws + 16777216);                               // 200 KB
    float* cw     = (float*)(ws + 16977920);                               // 200 KB
    float* bcat   = (float*)(ws + 17178624);                               // 8 KB
    float* S      = (float*)(ws + 17186816);                               // 2 MB

    k_cvt<<<1024, 256, 0, stream>>>(Wa, wa_bf, 262144);
    k_build_wcat<<<2048, 256, 0, stream>>>(Wi, Wh, Wz, bi, bh, bz, wcat_bf, bcat);
    k_build_xcat<<<256, 256, 0, stream>>>(xt, h0, xcat_bf);
    k_hlin<<<256, 512, 0, stream>>>(h0, Wha, bha, ba, hlin);
    k_scores<<<M_/128, 512, 0, stream>>>(att, wa_bf, hlin, Wo, bo, scores);
    k_softmax<<<256, 256, 0, stream>>>(scores, cw);
    k_z<<<dim3(2, 256), 256, 0, stream>>>(att, cw, xcat_bf);
    k_gemm2<<<dim3(16, 4), 256, 0, stream>>>(xcat_bf, wcat_bf, bcat, S);
    k_lstm<<<256, 512, 0, stream>>>(S, c0, out);
}